// Round 5
// baseline (240.320 us; speedup 1.0000x reference)
//
#include <hip/hip_runtime.h>

#define NG 4096
#define RELAX 0.1875f
#define BINCAP NG

__device__ __forceinline__ float linf(int i) { return -1.0f + (2.0f/63.0f)*(float)i; }
// center-first axis permutation: {7,8,6,9,5,10,4,11,3,12,2,13,1,14,0,15}
__device__ __forceinline__ int cperm(int i) { return (i & 1) ? 7 + ((i+1)>>1) : 7 - (i>>1); }

// ---- K1: fused masked-minmax reduce + center/scale + transform (1 block) ----
__global__ __launch_bounds__(1024) void gm_prep(
    const float* __restrict__ xyz, const float* __restrict__ scal,
    const float* __restrict__ rot, const float* __restrict__ opac,
    float4* __restrict__ posopa, float4* __restrict__ invrec)
{
  __shared__ float s_mn[3][1024];
  __shared__ float s_mx[3][1024];
  __shared__ float s_cs[4];
  const int tid = threadIdx.x;
  float mn0=1e10f, mn1=1e10f, mn2=1e10f;
  float mx0=-1e10f, mx1=-1e10f, mx2=-1e10f;
  #pragma unroll
  for (int k = 0; k < NG/1024; ++k) {
    int g = k*1024 + tid;
    float o = opac[g];
    float sig = 1.0f/(1.0f + __expf(-o));
    if (sig > 0.005f) {
      float x = xyz[3*g+0], y = xyz[3*g+1], z = xyz[3*g+2];
      mn0 = fminf(mn0,x); mn1 = fminf(mn1,y); mn2 = fminf(mn2,z);
      mx0 = fmaxf(mx0,x); mx1 = fmaxf(mx1,y); mx2 = fmaxf(mx2,z);
    }
  }
  s_mn[0][tid]=mn0; s_mn[1][tid]=mn1; s_mn[2][tid]=mn2;
  s_mx[0][tid]=mx0; s_mx[1][tid]=mx1; s_mx[2][tid]=mx2;
  __syncthreads();
  for (int s = 512; s > 0; s >>= 1) {
    if (tid < s) {
      #pragma unroll
      for (int k = 0; k < 3; ++k) {
        s_mn[k][tid] = fminf(s_mn[k][tid], s_mn[k][tid+s]);
        s_mx[k][tid] = fmaxf(s_mx[k][tid], s_mx[k][tid+s]);
      }
    }
    __syncthreads();
  }
  if (tid == 0) {
    float rmax = fmaxf(s_mx[0][0]-s_mn[0][0],
                 fmaxf(s_mx[1][0]-s_mn[1][0], s_mx[2][0]-s_mn[2][0]));
    s_cs[0] = (s_mn[0][0]+s_mx[0][0])*0.5f;
    s_cs[1] = (s_mn[1][0]+s_mx[1][0])*0.5f;
    s_cs[2] = (s_mn[2][0]+s_mx[2][0])*0.5f;
    s_cs[3] = 1.8f/rmax;
  }
  __syncthreads();
  const float cx=s_cs[0], cy=s_cs[1], cz=s_cs[2], scale=s_cs[3];
  #pragma unroll
  for (int k = 0; k < NG/1024; ++k) {
    int g = k*1024 + tid;
    float o = opac[g];
    float sig = 1.0f/(1.0f + __expf(-o));
    float opa = (sig > 0.005f) ? sig : 0.0f;
    float xs = (xyz[3*g+0]-cx)*scale;
    float ys = (xyz[3*g+1]-cy)*scale;
    float zs = (xyz[3*g+2]-cz)*scale;
    float sdx = __expf(scal[3*g+0])*scale;
    float sdy = __expf(scal[3*g+1])*scale;
    float sdz = __expf(scal[3*g+2])*scale;
    float qr=rot[4*g+0], qx=rot[4*g+1], qy=rot[4*g+2], qz=rot[4*g+3];
    float qn = 1.0f/sqrtf(qr*qr+qx*qx+qy*qy+qz*qz);
    qr*=qn; qx*=qn; qy*=qn; qz*=qn;
    float R00 = 1.0f-2.0f*(qy*qy+qz*qz), R01 = 2.0f*(qx*qy-qr*qz), R02 = 2.0f*(qx*qz+qr*qy);
    float R10 = 2.0f*(qx*qy+qr*qz), R11 = 1.0f-2.0f*(qx*qx+qz*qz), R12 = 2.0f*(qy*qz-qr*qx);
    float R20 = 2.0f*(qx*qz-qr*qy), R21 = 2.0f*(qy*qz+qr*qx), R22 = 1.0f-2.0f*(qx*qx+qy*qy);
    float L00=R00*sdx, L01=R01*sdy, L02=R02*sdz;
    float L10=R10*sdx, L11=R11*sdy, L12=R12*sdz;
    float L20=R20*sdx, L21=R21*sdy, L22=R22*sdz;
    float a = L00*L00+L01*L01+L02*L02;
    float b = L00*L10+L01*L11+L02*L12;
    float cc= L00*L20+L01*L21+L02*L22;
    float d = L10*L10+L11*L11+L12*L12;
    float e = L10*L20+L11*L21+L12*L22;
    float f = L20*L20+L21*L21+L22*L22;
    float det = a*d*f + 2.0f*e*cc*b - e*e*a - cc*cc*d - b*b*f + 1e-24f;
    float idt = 1.0f/det;
    float ia=(d*f-e*e)*idt, ib=(e*cc-b*f)*idt, ic=(e*b-cc*d)*idt;
    float id=(a*f-cc*cc)*idt, ie=(b*cc-e*a)*idt, iff=(a*d-b*b)*idt;
    posopa[g] = make_float4(xs, ys, zs, opa);
    // pre-scaled: power = px^2*I0.x + py^2*I0.w + pz^2*I1.y
    //                   + px*py*I0.y + px*pz*I0.z + py*pz*I1.x
    invrec[2*g+0] = make_float4(-0.5f*ia, -ib, -ic, -0.5f*id);
    invrec[2*g+1] = make_float4(-ie, -0.5f*iff, 0.0f, 0.0f);
  }
}

// ---- K2: 2D (bi,bj) binning: per-bin index lists ----
__global__ __launch_bounds__(512) void gm_bin(
    const float4* __restrict__ posopa,
    int* __restrict__ bincnt, unsigned short* __restrict__ binidx)
{
  __shared__ int s_cnt;
  __shared__ unsigned short s_idx[NG];   // 8 KB
  const int tid = threadIdx.x;
  const int b = blockIdx.x;
  const int bi = b >> 4, bj = b & 15;
  const float vminx = linf(bi*4) - RELAX, vmaxx = linf(bi*4+3) + RELAX;
  const float vminy = linf(bj*4) - RELAX, vmaxy = linf(bj*4+3) + RELAX;
  if (tid == 0) s_cnt = 0;
  __syncthreads();
  #pragma unroll
  for (int t = 0; t < NG/512; ++t) {
    int g = t*512 + tid;
    float4 P = posopa[g];
    if (P.w > 0.0f &&
        P.x > vminx && P.x < vmaxx &&
        P.y > vminy && P.y < vmaxy) {
      int slot = atomicAdd(&s_cnt, 1);
      s_idx[slot] = (unsigned short)g;
    }
  }
  __syncthreads();
  const int n = s_cnt;
  if (tid == 0) bincnt[b] = n;
  for (int t = tid; t < n; t += 512) binidx[b*BINCAP + t] = s_idx[t];
}

// ---- K3: eval — stream bin records from L2, branchless z, no staging ----
__global__ __launch_bounds__(512) void gm_evaluate(
    const float4* __restrict__ posopa, const float4* __restrict__ invrec,
    const int* __restrict__ bincnt, const unsigned short* __restrict__ binidx,
    float* __restrict__ out)
{
  __shared__ float s_acc[512];
  const int tid = threadIdx.x;
  const int b = blockIdx.x;
  const int bi = cperm(b >> 8), bj = cperm((b >> 4) & 15), bk = cperm(b & 15);
  const float vminz = linf(bk*4) - RELAX, vmaxz = linf(bk*4+3) + RELAX;
  const int p    = tid & 63;
  const int part = tid >> 6;            // 0..7 (8 waves, 1 record/wave/iter)
  const int sx = p >> 4, sy = (p >> 2) & 3, sz = p & 3;
  const float ptx = linf(bi*4+sx), pty = linf(bj*4+sy), ptz = linf(bk*4+sz);
  const unsigned short* mylist = binidx + (bi*16 + bj)*BINCAP;
  const int nxy = bincnt[bi*16 + bj];
  float acc = 0.0f;
  #pragma unroll 4
  for (int j = part; j < nxy; j += 8) {
    int g = mylist[j];                  // wave-uniform -> broadcast loads
    float4 P  = posopa[g];
    float4 I0 = invrec[2*g+0];
    float4 I1 = invrec[2*g+1];
    float px = ptx - P.x, py = pty - P.y, pz = ptz - P.z;
    float power = px*px*I0.x + py*py*I0.w + pz*pz*I1.y
                + px*py*I0.y + px*pz*I0.z + py*pz*I1.x;
    bool ok = (P.z > vminz) & (P.z < vmaxz) & (power <= 0.0f);
    acc += ok ? P.w * __expf(power) : 0.0f;
  }
  s_acc[tid] = acc;
  __syncthreads();
  if (tid < 64) {
    float v = 0.0f;
    #pragma unroll
    for (int w = 0; w < 8; ++w) v += s_acc[tid + w*64];
    out[(bi*4+sx)*4096 + (bj*4+sy)*64 + (bk*4+sz)] = v;
  }
}

// ---- fallback (no binning) if ws too small: stream full set ----
__global__ __launch_bounds__(512) void gm_evaluate_nobin(
    const float4* __restrict__ posopa, const float4* __restrict__ invrec,
    float* __restrict__ out)
{
  __shared__ float s_acc[512];
  const int tid = threadIdx.x;
  const int b = blockIdx.x;
  const int bi = cperm(b >> 8), bj = cperm((b >> 4) & 15), bk = cperm(b & 15);
  const float vminx = linf(bi*4) - RELAX, vmaxx = linf(bi*4+3) + RELAX;
  const float vminy = linf(bj*4) - RELAX, vmaxy = linf(bj*4+3) + RELAX;
  const float vminz = linf(bk*4) - RELAX, vmaxz = linf(bk*4+3) + RELAX;
  const int p    = tid & 63;
  const int part = tid >> 6;
  const int sx = p >> 4, sy = (p >> 2) & 3, sz = p & 3;
  const float ptx = linf(bi*4+sx), pty = linf(bj*4+sy), ptz = linf(bk*4+sz);
  float acc = 0.0f;
  #pragma unroll 2
  for (int j = part; j < NG; j += 8) {
    float4 P  = posopa[j];
    float4 I0 = invrec[2*j+0];
    float4 I1 = invrec[2*j+1];
    float px = ptx - P.x, py = pty - P.y, pz = ptz - P.z;
    float power = px*px*I0.x + py*py*I0.w + pz*pz*I1.y
                + px*py*I0.y + px*pz*I0.z + py*pz*I1.x;
    bool ok = (P.w > 0.0f) &
              (P.x > vminx) & (P.x < vmaxx) &
              (P.y > vminy) & (P.y < vmaxy) &
              (P.z > vminz) & (P.z < vmaxz) & (power <= 0.0f);
    acc += ok ? P.w * __expf(power) : 0.0f;
  }
  s_acc[tid] = acc;
  __syncthreads();
  if (tid < 64) {
    float v = 0.0f;
    #pragma unroll
    for (int w = 0; w < 8; ++w) v += s_acc[tid + w*64];
    out[(bi*4+sx)*4096 + (bj*4+sy)*64 + (bk*4+sz)] = v;
  }
}

extern "C" void kernel_launch(void* const* d_in, const int* in_sizes, int n_in,
                              void* d_out, int out_size, void* d_ws, size_t ws_size,
                              hipStream_t stream) {
  const float* xyz  = (const float*)d_in[0];
  const float* scal = (const float*)d_in[1];
  const float* rot  = (const float*)d_in[2];
  const float* opac = (const float*)d_in[3];
  float* out = (float*)d_out;
  char* ws = (char*)d_ws;
  float4* posopa = (float4*)(ws);                       //  64 KB
  float4* invrec = (float4*)(ws + 65536);               // 128 KB
  int*    bincnt = (int*)(ws + 65536 + 131072);         //   1 KB
  unsigned short* binidx = (unsigned short*)(bincnt + 256); // 2 MB
  const size_t needed = 65536 + 131072 + 1024 + (size_t)256*BINCAP*2;

  gm_prep<<<1, 1024, 0, stream>>>(xyz, scal, rot, opac, posopa, invrec);
  if (ws_size >= needed) {
    gm_bin     <<<256,  512, 0, stream>>>(posopa, bincnt, binidx);
    gm_evaluate<<<4096, 512, 0, stream>>>(posopa, invrec, bincnt, binidx, out);
  } else {
    gm_evaluate_nobin<<<4096, 512, 0, stream>>>(posopa, invrec, out);
  }
}

// Round 6
// 163.469 us; speedup vs baseline: 1.4701x; 1.4701x over previous
//
#include <hip/hip_runtime.h>

#define NG 4096
#define RELAX 0.1875f
#define CH 256
#define LISTCAP (64*NG)   // provable: <=4 blocks/axis span -> <=64 entries/gaussian

__device__ __forceinline__ float linf(int i) { return -1.0f + (2.0f/63.0f)*(float)i; }
// center-first axis permutation: heavy central blocks launch first
__device__ __forceinline__ int cperm(int i) { return (i & 1) ? 7 + ((i+1)>>1) : 7 - (i>>1); }

// ---- K1: fused masked-minmax reduce + center/scale + transform (1 block) ----
__global__ __launch_bounds__(1024) void gm_prep(
    const float* __restrict__ xyz, const float* __restrict__ scal,
    const float* __restrict__ rot, const float* __restrict__ opac,
    float4* __restrict__ posopa, float4* __restrict__ invrec,
    int* __restrict__ cursor)
{
  __shared__ float s_mn[3][1024];
  __shared__ float s_mx[3][1024];
  __shared__ float s_cs[4];
  const int tid = threadIdx.x;
  if (tid == 0) *cursor = 0;          // CSR allocator init (ws is poisoned)
  float mn0=1e10f, mn1=1e10f, mn2=1e10f;
  float mx0=-1e10f, mx1=-1e10f, mx2=-1e10f;
  #pragma unroll
  for (int k = 0; k < NG/1024; ++k) {
    int g = k*1024 + tid;
    float o = opac[g];
    float sig = 1.0f/(1.0f + __expf(-o));
    if (sig > 0.005f) {
      float x = xyz[3*g+0], y = xyz[3*g+1], z = xyz[3*g+2];
      mn0 = fminf(mn0,x); mn1 = fminf(mn1,y); mn2 = fminf(mn2,z);
      mx0 = fmaxf(mx0,x); mx1 = fmaxf(mx1,y); mx2 = fmaxf(mx2,z);
    }
  }
  s_mn[0][tid]=mn0; s_mn[1][tid]=mn1; s_mn[2][tid]=mn2;
  s_mx[0][tid]=mx0; s_mx[1][tid]=mx1; s_mx[2][tid]=mx2;
  __syncthreads();
  for (int s = 512; s > 0; s >>= 1) {
    if (tid < s) {
      #pragma unroll
      for (int k = 0; k < 3; ++k) {
        s_mn[k][tid] = fminf(s_mn[k][tid], s_mn[k][tid+s]);
        s_mx[k][tid] = fmaxf(s_mx[k][tid], s_mx[k][tid+s]);
      }
    }
    __syncthreads();
  }
  if (tid == 0) {
    float rmax = fmaxf(s_mx[0][0]-s_mn[0][0],
                 fmaxf(s_mx[1][0]-s_mn[1][0], s_mx[2][0]-s_mn[2][0]));
    s_cs[0] = (s_mn[0][0]+s_mx[0][0])*0.5f;
    s_cs[1] = (s_mn[1][0]+s_mx[1][0])*0.5f;
    s_cs[2] = (s_mn[2][0]+s_mx[2][0])*0.5f;
    s_cs[3] = 1.8f/rmax;
  }
  __syncthreads();
  const float cx=s_cs[0], cy=s_cs[1], cz=s_cs[2], scale=s_cs[3];
  #pragma unroll
  for (int k = 0; k < NG/1024; ++k) {
    int g = k*1024 + tid;
    float o = opac[g];
    float sig = 1.0f/(1.0f + __expf(-o));
    float opa = (sig > 0.005f) ? sig : 0.0f;
    float xs = (xyz[3*g+0]-cx)*scale;
    float ys = (xyz[3*g+1]-cy)*scale;
    float zs = (xyz[3*g+2]-cz)*scale;
    float sdx = __expf(scal[3*g+0])*scale;
    float sdy = __expf(scal[3*g+1])*scale;
    float sdz = __expf(scal[3*g+2])*scale;
    float qr=rot[4*g+0], qx=rot[4*g+1], qy=rot[4*g+2], qz=rot[4*g+3];
    float qn = 1.0f/sqrtf(qr*qr+qx*qx+qy*qy+qz*qz);
    qr*=qn; qx*=qn; qy*=qn; qz*=qn;
    float R00 = 1.0f-2.0f*(qy*qy+qz*qz), R01 = 2.0f*(qx*qy-qr*qz), R02 = 2.0f*(qx*qz+qr*qy);
    float R10 = 2.0f*(qx*qy+qr*qz), R11 = 1.0f-2.0f*(qx*qx+qz*qz), R12 = 2.0f*(qy*qz-qr*qx);
    float R20 = 2.0f*(qx*qz-qr*qy), R21 = 2.0f*(qy*qz+qr*qx), R22 = 1.0f-2.0f*(qx*qx+qy*qy);
    float L00=R00*sdx, L01=R01*sdy, L02=R02*sdz;
    float L10=R10*sdx, L11=R11*sdy, L12=R12*sdz;
    float L20=R20*sdx, L21=R21*sdy, L22=R22*sdz;
    float a = L00*L00+L01*L01+L02*L02;
    float b = L00*L10+L01*L11+L02*L12;
    float cc= L00*L20+L01*L21+L02*L22;
    float d = L10*L10+L11*L11+L12*L12;
    float e = L10*L20+L11*L21+L12*L22;
    float f = L20*L20+L21*L21+L22*L22;
    float det = a*d*f + 2.0f*e*cc*b - e*e*a - cc*cc*d - b*b*f + 1e-24f;
    float idt = 1.0f/det;
    float ia=(d*f-e*e)*idt, ib=(e*cc-b*f)*idt, ic=(e*b-cc*d)*idt;
    float id=(a*f-cc*cc)*idt, ie=(b*cc-e*a)*idt, iff=(a*d-b*b)*idt;
    posopa[g] = make_float4(xs, ys, zs, opa);
    // pre-scaled: power = px^2*I0.x + py^2*I0.w + pz^2*I1.y
    //                   + px*py*I0.y + px*pz*I0.z + py*pz*I1.x
    invrec[2*g+0] = make_float4(-0.5f*ia, -ib, -ic, -0.5f*id);
    invrec[2*g+1] = make_float4(-ie, -0.5f*iff, 0.0f, 0.0f);
  }
}

// ---- K2: exact 3D CSR lists. One block per xy-bin; z-mask uses the exact
//      reference predicate (same linf/RELAX fp ops as the box test). ----
__global__ __launch_bounds__(256) void gm_bin3d(
    const float4* __restrict__ posopa,
    int* __restrict__ cursor, int* __restrict__ ofs, int* __restrict__ cnt,
    unsigned short* __restrict__ list)
{
  __shared__ unsigned short s_idx[NG];   // 8 KB survivor ids
  __shared__ unsigned short s_msk[NG];   // 8 KB z-block masks
  __shared__ int s_zcnt[16], s_zcur[16];
  __shared__ int s_n, s_base;
  const int tid = threadIdx.x;
  const int b = blockIdx.x;
  const int bi = b >> 4, bj = b & 15;
  const float vminx = linf(bi*4)-RELAX, vmaxx = linf(bi*4+3)+RELAX;
  const float vminy = linf(bj*4)-RELAX, vmaxy = linf(bj*4+3)+RELAX;
  if (tid == 0) s_n = 0;
  if (tid < 16) s_zcnt[tid] = 0;
  __syncthreads();
  #pragma unroll
  for (int t = 0; t < NG/256; ++t) {
    int g = t*256 + tid;
    float4 P = posopa[g];
    if (P.w > 0.0f && P.x > vminx && P.x < vmaxx &&
        P.y > vminy && P.y < vmaxy) {
      unsigned m = 0;
      #pragma unroll
      for (int bk = 0; bk < 16; ++bk) {
        bool in = (P.z > linf(bk*4)-RELAX) && (P.z < linf(bk*4+3)+RELAX);
        m |= (in ? 1u : 0u) << bk;
      }
      if (m) {
        int slot = atomicAdd(&s_n, 1);
        s_idx[slot] = (unsigned short)g;
        s_msk[slot] = (unsigned short)m;
        unsigned mm = m;
        while (mm) { int z = __ffs(mm)-1; mm &= mm-1; atomicAdd(&s_zcnt[z],1); }
      }
    }
  }
  __syncthreads();
  if (tid == 0) {
    int tot = 0;
    #pragma unroll
    for (int z = 0; z < 16; ++z) tot += s_zcnt[z];
    s_base = atomicAdd(cursor, tot);      // device-scope allocator
    int run = s_base;
    #pragma unroll
    for (int z = 0; z < 16; ++z) {
      ofs[b*16+z] = run; cnt[b*16+z] = s_zcnt[z]; s_zcur[z] = run;
      run += s_zcnt[z];
    }
  }
  __syncthreads();
  const int n = s_n;
  for (int t = tid; t < n; t += 256) {
    unsigned m = s_msk[t];
    unsigned short gi = s_idx[t];
    while (m) {
      int z = __ffs(m)-1; m &= m-1;
      int pos = atomicAdd(&s_zcur[z], 1);
      list[pos] = gi;
    }
  }
}

// ---- K3: eval. Exact list, parallel-gather LDS staging, double-buffered,
//      zero tests in hot loop except power<=0 select. ----
__global__ __launch_bounds__(256) void gm_evaluate(
    const float4* __restrict__ posopa, const float4* __restrict__ invrec,
    const int* __restrict__ ofs, const int* __restrict__ cnt,
    const unsigned short* __restrict__ list, float* __restrict__ out)
{
  __shared__ float4 sA[2][CH];   // P        8 KB
  __shared__ float4 sB[2][CH];   // I0       8 KB
  __shared__ float2 sC[2][CH];   // I1       4 KB
  __shared__ float  s_acc[256];
  const int tid = threadIdx.x;
  const int b = blockIdx.x;
  const int bi = cperm(b >> 8), bj = cperm((b >> 4) & 15), bk = cperm(b & 15);
  const int key = ((bi*16+bj) << 4) | bk;
  const int n = cnt[key];
  const unsigned short* lst = list + ofs[key];
  const int p = tid & 63, part = tid >> 6;   // 4 waves, 4-way record split
  const int sx = p >> 4, sy = (p >> 2) & 3, sz = p & 3;
  const float ptx = linf(bi*4+sx), pty = linf(bj*4+sy), ptz = linf(bk*4+sz);
  float acc = 0.0f;

  // stage chunk 0 (parallel gather: 1 record/thread)
  if (tid < min(n, CH)) {
    int g = lst[tid];
    sA[0][tid] = posopa[g];
    sB[0][tid] = invrec[2*g];
    float4 t = invrec[2*g+1];
    sC[0][tid] = make_float2(t.x, t.y);
  }
  __syncthreads();
  int buf = 0;
  for (int c0 = 0; c0 < n; c0 += CH) {
    int nxt = c0 + CH;
    if (nxt < n && tid < min(n - nxt, CH)) {   // prefetch next chunk
      int g = lst[nxt + tid];
      sA[buf^1][tid] = posopa[g];
      sB[buf^1][tid] = invrec[2*g];
      float4 t = invrec[2*g+1];
      sC[buf^1][tid] = make_float2(t.x, t.y);
    }
    const int lim = min(n - c0, CH);
    #pragma unroll 2
    for (int j = part; j < lim; j += 4) {      // wave-uniform LDS broadcasts
      float4 P  = sA[buf][j];
      float4 I0 = sB[buf][j];
      float2 I1 = sC[buf][j];
      float px = ptx - P.x, py = pty - P.y, pz = ptz - P.z;
      float power = px*px*I0.x + py*py*I0.w + pz*pz*I1.y
                  + px*py*I0.y + px*pz*I0.z + py*pz*I1.x;
      acc += (power <= 0.0f) ? P.w * __expf(power) : 0.0f;
    }
    __syncthreads();
    buf ^= 1;
  }
  s_acc[tid] = acc;
  __syncthreads();
  if (tid < 64) {
    float v = s_acc[tid] + s_acc[tid+64] + s_acc[tid+128] + s_acc[tid+192];
    out[(bi*4+sx)*4096 + (bj*4+sy)*64 + (bk*4+sz)] = v;
  }
}

// ---- fallback (no ws): stream full set, branchless ----
__global__ __launch_bounds__(512) void gm_evaluate_nobin(
    const float4* __restrict__ posopa, const float4* __restrict__ invrec,
    float* __restrict__ out)
{
  __shared__ float s_acc[512];
  const int tid = threadIdx.x;
  const int b = blockIdx.x;
  const int bi = cperm(b >> 8), bj = cperm((b >> 4) & 15), bk = cperm(b & 15);
  const float vminx = linf(bi*4) - RELAX, vmaxx = linf(bi*4+3) + RELAX;
  const float vminy = linf(bj*4) - RELAX, vmaxy = linf(bj*4+3) + RELAX;
  const float vminz = linf(bk*4) - RELAX, vmaxz = linf(bk*4+3) + RELAX;
  const int p = tid & 63, part = tid >> 6;
  const int sx = p >> 4, sy = (p >> 2) & 3, sz = p & 3;
  const float ptx = linf(bi*4+sx), pty = linf(bj*4+sy), ptz = linf(bk*4+sz);
  float acc = 0.0f;
  #pragma unroll 2
  for (int j = part; j < NG; j += 8) {
    float4 P  = posopa[j];
    float4 I0 = invrec[2*j+0];
    float4 I1 = invrec[2*j+1];
    float px = ptx - P.x, py = pty - P.y, pz = ptz - P.z;
    float power = px*px*I0.x + py*py*I0.w + pz*pz*I1.y
                + px*py*I0.y + px*pz*I0.z + py*pz*I1.x;
    bool ok = (P.w > 0.0f) &
              (P.x > vminx) & (P.x < vmaxx) &
              (P.y > vminy) & (P.y < vmaxy) &
              (P.z > vminz) & (P.z < vmaxz) & (power <= 0.0f);
    acc += ok ? P.w * __expf(power) : 0.0f;
  }
  s_acc[tid] = acc;
  __syncthreads();
  if (tid < 64) {
    float v = 0.0f;
    #pragma unroll
    for (int w = 0; w < 8; ++w) v += s_acc[tid + w*64];
    out[(bi*4+sx)*4096 + (bj*4+sy)*64 + (bk*4+sz)] = v;
  }
}

extern "C" void kernel_launch(void* const* d_in, const int* in_sizes, int n_in,
                              void* d_out, int out_size, void* d_ws, size_t ws_size,
                              hipStream_t stream) {
  const float* xyz  = (const float*)d_in[0];
  const float* scal = (const float*)d_in[1];
  const float* rot  = (const float*)d_in[2];
  const float* opac = (const float*)d_in[3];
  float* out = (float*)d_out;
  char* ws = (char*)d_ws;
  float4* posopa = (float4*)(ws);                         //  64 KB
  float4* invrec = (float4*)(ws + 65536);                 // 128 KB
  int*    cursor = (int*)(ws + 65536 + 131072);           //  16 B (padded)
  int*    ofs    = (int*)(ws + 65536 + 131072 + 16);      //  16 KB
  int*    cnt    = (int*)(ws + 65536 + 131072 + 16 + 16384);            // 16 KB
  unsigned short* list = (unsigned short*)(ws + 65536 + 131072 + 16 + 32768); // 512 KB
  const size_t needed = 65536 + 131072 + 16 + 32768 + (size_t)LISTCAP*2;

  gm_prep<<<1, 1024, 0, stream>>>(xyz, scal, rot, opac, posopa, invrec, cursor);
  if (ws_size >= needed) {
    gm_bin3d   <<<256,  256, 0, stream>>>(posopa, cursor, ofs, cnt, list);
    gm_evaluate<<<4096, 256, 0, stream>>>(posopa, invrec, ofs, cnt, list, out);
  } else {
    gm_evaluate_nobin<<<4096, 512, 0, stream>>>(posopa, invrec, out);
  }
}